// Round 11
// baseline (35689.984 us; speedup 1.0000x reference)
//
#include <hip/hip_runtime.h>

// 2-layer GRU scan: L=512, B=256, D=H=512, 3H=1536.
// Persistent cooperative kernel: 256 blocks (1/CU, LDS-pinned) x 512 threads.
// 8 groups x 32 blocks (g=bid&7); group owns 32 batch rows.
// R11 = R10 with the asm operand-order fix (offset: BEFORE sc0 sc1).
// TAG-IN-DATA dataflow. h stored as u32 {tag16|fp16} in ring-4 buffers
// (sc0 sc1 write-through, R2/R6/R9-proven transport). Producers never drain
// before signaling — the data IS the signal. Consumers poll-load their MFMA
// fragments directly (asm 16-load + vmcnt + tag-check + ballot + retry).
// Cross-block chain per step: ~2 fabric ops (was ~5-6 in R2/R4/R9 = 17us/step).
// Roles free-run (R6 structure, no __syncthreads in loop): 0=gh0+ep0+h0store,
// 1=gi0 producer (ahead), 2=gi1+ep1+h1store+y, 3=gh1 producer. LDS handoffs
// with acquire/release flags (R6-proven). WAR: ring-4 + consumed-counters
// (atomic store / poll64, off critical path). Rings zeroed every call.

#define LSEQ 512
#define TH3 1536

// ws layout (bytes); total ~10.7 MB
#define WT_OFF   0                         // half WT[4][32][16][3][64][8] = 6291456
#define H0R_OFF  6291456                   // u32 h0ring[8][4][32][512]    = 2097152
#define H1R_OFF  8388608                   // u32 h1ring[8][4][32][512]    = 2097152
#define C0_OFF   10485760                  // c0[8][64][128B]              = 65536
#define C2_OFF   10551296                  // c2[8][64][128B]              = 65536
#define C3_OFF   10616832                  // c3[8][64][128B]              = 65536

typedef _Float16 f16x8 __attribute__((ext_vector_type(8)));
typedef float f32x4 __attribute__((ext_vector_type(4)));
typedef unsigned int u32x4 __attribute__((ext_vector_type(4)));

__device__ __forceinline__ float sig_(float v) { return 1.0f / (1.0f + __expf(-v)); }
__device__ __forceinline__ float tanh_(float v) { return 2.0f / (1.0f + __expf(-2.0f * v)) - 1.0f; }

__device__ __forceinline__ void astore(unsigned int* p, unsigned int v) {
  __hip_atomic_store(p, v, __ATOMIC_RELAXED, __HIP_MEMORY_SCOPE_AGENT);
}
__device__ __forceinline__ unsigned int aload(unsigned int* p) {
  return __hip_atomic_load(p, __ATOMIC_RELAXED, __HIP_MEMORY_SCOPE_AGENT);
}
__device__ __forceinline__ void poll64(char* base, int lane, unsigned int target) {
  unsigned int* p = (unsigned int*)(base + lane * 128);
  while (__ballot(aload(p) >= target) != ~0ull) __builtin_amdgcn_s_sleep(1);
}
__device__ __forceinline__ void lds_post(unsigned int* f, unsigned int v) {
  __hip_atomic_store(f, v, __ATOMIC_RELEASE, __HIP_MEMORY_SCOPE_WORKGROUP);
}
__device__ __forceinline__ void lds_poll(unsigned int* f, unsigned int v) {
  while (__hip_atomic_load(f, __ATOMIC_ACQUIRE, __HIP_MEMORY_SCOPE_WORKGROUP) < v) {}
}
__device__ __forceinline__ void storeu32(unsigned int* p, unsigned int v) {
  asm volatile("global_store_dword %0, %1, off sc0 sc1" :: "v"(p), "v"(v) : "memory");
}
__device__ __forceinline__ unsigned int f16bits(float h) {
  return (unsigned int)__builtin_bit_cast(unsigned short, (_Float16)h);
}

// Poll-load 8 MFMA A-fragments (kc..kc+7): 16 dwordx4 sc1 loads + vmcnt in ONE
// asm block (outputs valid on exit), tag-check all 32 u32/lane, ballot, retry.
__device__ __forceinline__ void pollload8(const unsigned int* p, unsigned int tag, f16x8* dst) {
  u32x4 r0, r1, r2, r3, r4, r5, r6, r7, r8, r9, r10, r11, r12, r13, r14, r15;
  for (;;) {
    asm volatile(
        "global_load_dwordx4 %0, %[p], off sc0 sc1\n\t"
        "global_load_dwordx4 %1, %[p], off offset:16 sc0 sc1\n\t"
        "global_load_dwordx4 %2, %[p], off offset:128 sc0 sc1\n\t"
        "global_load_dwordx4 %3, %[p], off offset:144 sc0 sc1\n\t"
        "global_load_dwordx4 %4, %[p], off offset:256 sc0 sc1\n\t"
        "global_load_dwordx4 %5, %[p], off offset:272 sc0 sc1\n\t"
        "global_load_dwordx4 %6, %[p], off offset:384 sc0 sc1\n\t"
        "global_load_dwordx4 %7, %[p], off offset:400 sc0 sc1\n\t"
        "global_load_dwordx4 %8, %[p], off offset:512 sc0 sc1\n\t"
        "global_load_dwordx4 %9, %[p], off offset:528 sc0 sc1\n\t"
        "global_load_dwordx4 %10, %[p], off offset:640 sc0 sc1\n\t"
        "global_load_dwordx4 %11, %[p], off offset:656 sc0 sc1\n\t"
        "global_load_dwordx4 %12, %[p], off offset:768 sc0 sc1\n\t"
        "global_load_dwordx4 %13, %[p], off offset:784 sc0 sc1\n\t"
        "global_load_dwordx4 %14, %[p], off offset:896 sc0 sc1\n\t"
        "global_load_dwordx4 %15, %[p], off offset:912 sc0 sc1\n\t"
        "s_waitcnt vmcnt(0)"
        : "=&v"(r0), "=&v"(r1), "=&v"(r2), "=&v"(r3), "=&v"(r4), "=&v"(r5), "=&v"(r6), "=&v"(r7),
          "=&v"(r8), "=&v"(r9), "=&v"(r10), "=&v"(r11), "=&v"(r12), "=&v"(r13), "=&v"(r14),
          "=&v"(r15)
        : [p] "v"(p)
        : "memory");
    __builtin_amdgcn_sched_barrier(0);
    bool ok = true;
#define CKT(v) ok &= ((v[0] >> 16) == tag) & ((v[1] >> 16) == tag) & ((v[2] >> 16) == tag) & ((v[3] >> 16) == tag)
    CKT(r0); CKT(r1); CKT(r2); CKT(r3); CKT(r4); CKT(r5); CKT(r6); CKT(r7);
    CKT(r8); CKT(r9); CKT(r10); CKT(r11); CKT(r12); CKT(r13); CKT(r14); CKT(r15);
#undef CKT
    if (__ballot(ok) == ~0ull) break;
    __builtin_amdgcn_s_sleep(1);
  }
#define PK(d, lo, hi)                                              \
  {                                                                \
    union { unsigned int u[4]; f16x8 h; } t_;                      \
    t_.u[0] = (lo[0] & 0xffffu) | (lo[1] << 16);                   \
    t_.u[1] = (lo[2] & 0xffffu) | (lo[3] << 16);                   \
    t_.u[2] = (hi[0] & 0xffffu) | (hi[1] << 16);                   \
    t_.u[3] = (hi[2] & 0xffffu) | (hi[3] << 16);                   \
    d = t_.h;                                                      \
  }
  PK(dst[0], r0, r1); PK(dst[1], r2, r3); PK(dst[2], r4, r5); PK(dst[3], r6, r7);
  PK(dst[4], r8, r9); PK(dst[5], r10, r11); PK(dst[6], r12, r13); PK(dst[7], r14, r15);
#undef PK
}

// Weight transpose fp32 -> fp16 MFMA B-fragment layout (unchanged) + zero rings.
__global__ void prep_kernel(const float* __restrict__ Wh0, const float* __restrict__ Wi1,
                            const float* __restrict__ Wh1, const float* __restrict__ Wi0,
                            char* __restrict__ ws) {
  const int b = blockIdx.x;          // 2048 blocks
  const int w = b >> 9;              // 0:Wh0 1:Wi1 2:Wh1 3:Wi0
  const int k = b & 511;
  const float* src = (w == 0) ? Wh0 : (w == 1) ? Wi1 : (w == 2) ? Wh1 : Wi0;
  _Float16* dst = (_Float16*)(ws + WT_OFF);
  const int kc = k >> 5;
  const int lthi = ((k >> 3) & 3) << 4;
  const int e = k & 7;
  for (int col = threadIdx.x; col < TH3; col += 256) {
    float v = src[(size_t)k * TH3 + col];
    int nt = col >> 9, c = col & 511, cid = c >> 4, j = c & 15;
    size_t idx = (size_t)(w * 32 + cid) * 24576 + (size_t)((kc * 3 + nt) * 64 + lthi + j) * 8 + e;
    dst[idx] = (_Float16)v;
  }
  // zero h rings + consumed counters (every call; visible via end-of-dispatch flush)
  unsigned int* z = (unsigned int*)(ws + H0R_OFF);
  for (int i = b * 256 + threadIdx.x; i < 1097728; i += 2048 * 256) z[i] = 0u;
}

__global__ void __launch_bounds__(512, 2)
gru_kernel(const float* __restrict__ carry, const float* __restrict__ x,
           const float* __restrict__ bh0, const float* __restrict__ bh1,
           float* __restrict__ out, char* __restrict__ ws) {
  extern __shared__ char smem[];
  _Float16* Wlds = (_Float16*)smem;        // 147456 B: Wh0,Wi1,Wh1 fragment slices
  float* gi0buf = (float*)(smem + 147456); // 6144 B: [3 nt][32 row][16 col]
  float* gh1buf = (float*)(smem + 153600); // 6144 B
  __shared__ unsigned int sf[8];  // 0,1:gi0_rdy[mh] 2,3:gi0_cons 4,5:gh1_rdy 6,7:gh1_cons

  const int tid = threadIdx.x;
  const int wid = tid >> 6, lane = tid & 63;
  const int l16 = lane & 15, lhi = lane >> 4;
  const int mhalf = wid & 1, role = wid >> 1;  // 0:gh0+ep0+h0st 1:gi0 2:gi1+ep1+h1st+y 3:gh1
  const int g = blockIdx.x & 7, cid = blockIdx.x >> 3;

  if (tid < 8) sf[tid] = 0u;

  _Float16* wt = (_Float16*)(ws + WT_OFF);
  unsigned int* h0r = (unsigned int*)(ws + H0R_OFF) + (size_t)g * 4 * 16384;  // [4 slot][32 r][512 c]
  unsigned int* h1r = (unsigned int*)(ws + H1R_OFF) + (size_t)g * 4 * 16384;
  char* c0b = ws + C0_OFF + (size_t)g * 64 * 128;
  char* c2b = ws + C2_OFF + (size_t)g * 64 * 128;
  char* c3b = ws + C3_OFF + (size_t)g * 64 * 128;
  unsigned int* c0me = (unsigned int*)(c0b + (cid * 2 + mhalf) * 128);
  unsigned int* c2me = (unsigned int*)(c2b + (cid * 2 + mhalf) * 128);
  unsigned int* c3me = (unsigned int*)(c3b + (cid * 2 + mhalf) * 128);

  // Stage recurrent-weight fragments into LDS.
  for (int w = 0; w < 3; ++w) {
    const f16x8* s8 = (const f16x8*)(wt + (size_t)(w * 32 + cid) * 24576);
    f16x8* d8 = (f16x8*)(Wlds + w * 24576);
    for (int i = tid; i < 3072; i += 512) d8[i] = s8[i];
  }
  __syncthreads();  // weights + sf ready; ONLY block-wide sync

  const f16x8* Wb0 = (const f16x8*)Wlds;                // Wh0 (LDS)
  const f16x8* Wb1 = (const f16x8*)(Wlds + 24576);      // Wi1 (LDS)
  const f16x8* Wb2 = (const f16x8*)(Wlds + 2 * 24576);  // Wh1 (LDS)
  const f16x8* WbX = (const f16x8*)(wt + (size_t)(3 * 32 + cid) * 24576);  // Wi0 (L2)

  const int hcol = cid * 16 + l16;
  const int rowq0 = mhalf * 16 + 4 * lhi;   // C/D rows (m89-verified)
  const int arow = mhalf * 16 + l16;        // A-fragment row

  if (role == 0) {  // ======== layer0: consume h0[t-1], gh0, epilogue, store h0[t] ========
    float bR = bh0[hcol], bZ = bh0[512 + hcol], bN = bh0[1024 + hcol];
    f32x4 hst;
#pragma unroll
    for (int q = 0; q < 4; ++q) {  // prefill h0[-1] (slot 3, tag 1)
      float h = carry[(size_t)(g * 32 + rowq0 + q) * 1024 + hcol];
      hst[q] = h;
      storeu32(h0r + 3 * 16384 + (rowq0 + q) * 512 + hcol, (1u << 16) | f16bits(h));
    }
    for (int t = 0; t < LSEQ; ++t) {
      if (t >= 4) { poll64(c0b, lane, (unsigned)(t - 2)); poll64(c2b, lane, (unsigned)(t - 2)); }
      const unsigned int* p = h0r + ((t + 3) & 3) * 16384 + arow * 512 + 8 * lhi;
      f16x8 afr[16];
      pollload8(p, (unsigned)(t + 1), afr);
      pollload8(p + 256, (unsigned)(t + 1), afr + 8);
      if (lane == 0) astore(c0me, (unsigned)(t + 1));
      f32x4 a0 = {0,0,0,0}, a1 = {0,0,0,0}, a2 = {0,0,0,0};
#pragma unroll
      for (int kc = 0; kc < 16; ++kc) {
        a0 = __builtin_amdgcn_mfma_f32_16x16x32_f16(afr[kc], Wb0[(kc*3+0)*64+lane], a0, 0,0,0);
        a1 = __builtin_amdgcn_mfma_f32_16x16x32_f16(afr[kc], Wb0[(kc*3+1)*64+lane], a1, 0,0,0);
        a2 = __builtin_amdgcn_mfma_f32_16x16x32_f16(afr[kc], Wb0[(kc*3+2)*64+lane], a2, 0,0,0);
      }
      lds_poll(&sf[0 + mhalf], (unsigned)(t + 1));  // gi0[t] ready
      float hnew[4];
#pragma unroll
      for (int q = 0; q < 4; ++q) {
        const int row = rowq0 + q;
        float r = sig_(gi0buf[(0*32 + row)*16 + l16] + a0[q] + bR);
        float z = sig_(gi0buf[(1*32 + row)*16 + l16] + a1[q] + bZ);
        float n = tanh_(gi0buf[(2*32 + row)*16 + l16] + r * (a2[q] + bN));
        hnew[q] = (1.0f - z) * n + z * hst[q];
        hst[q] = hnew[q];
      }
      if (lane == 0) lds_post(&sf[2 + mhalf], (unsigned)(t + 1));  // consumed gi0[t]
      const unsigned int tg = (unsigned)(t + 2) << 16;
#pragma unroll
      for (int q = 0; q < 4; ++q)
        storeu32(h0r + (t & 3) * 16384 + (rowq0 + q) * 512 + hcol, tg | f16bits(hnew[q]));
      if (t == LSEQ - 1) {
#pragma unroll
        for (int q = 0; q < 4; ++q)
          out[(size_t)(g * 32 + rowq0 + q) * 1024 + hcol] = hst[q];  // carry h0
      }
    }
  } else if (role == 1) {  // ======== gi0 = x[t] @ Wi0 producer (runs ahead) ========
    for (int t = 0; t < LSEQ; ++t) {
      const float* xp = x + ((size_t)t * 256 + g * 32 + arow) * 512 + 8 * lhi;
      f32x4 a0 = {0,0,0,0}, a1 = {0,0,0,0}, a2 = {0,0,0,0};
#pragma unroll
      for (int kc = 0; kc < 16; ++kc) {
        f32x4 xa = *(const f32x4*)(xp + kc * 32);
        f32x4 xb = *(const f32x4*)(xp + kc * 32 + 4);
        f16x8 a;
        a[0]=(_Float16)xa[0]; a[1]=(_Float16)xa[1]; a[2]=(_Float16)xa[2]; a[3]=(_Float16)xa[3];
        a[4]=(_Float16)xb[0]; a[5]=(_Float16)xb[1]; a[6]=(_Float16)xb[2]; a[7]=(_Float16)xb[3];
        a0 = __builtin_amdgcn_mfma_f32_16x16x32_f16(a, WbX[(kc*3+0)*64+lane], a0, 0,0,0);
        a1 = __builtin_amdgcn_mfma_f32_16x16x32_f16(a, WbX[(kc*3+1)*64+lane], a1, 0,0,0);
        a2 = __builtin_amdgcn_mfma_f32_16x16x32_f16(a, WbX[(kc*3+2)*64+lane], a2, 0,0,0);
      }
      lds_poll(&sf[2 + mhalf], (unsigned)t);  // role0 consumed gi0[t-1]
#pragma unroll
      for (int q = 0; q < 4; ++q) {
        const int row = rowq0 + q;
        gi0buf[(0*32 + row)*16 + l16] = a0[q];
        gi0buf[(1*32 + row)*16 + l16] = a1[q];
        gi0buf[(2*32 + row)*16 + l16] = a2[q];
      }
      if (lane == 0) lds_post(&sf[0 + mhalf], (unsigned)(t + 1));
    }
  } else if (role == 2) {  // ======== layer1: consume h0[t], gi1, epilogue, store h1[t], y ========
    float bR = bh1[hcol], bZ = bh1[512 + hcol], bN = bh1[1024 + hcol];
    f32x4 hst;
#pragma unroll
    for (int q = 0; q < 4; ++q) {  // prefill h1[-1] (slot 3, tag 1)
      float h = carry[(size_t)(g * 32 + rowq0 + q) * 1024 + 512 + hcol];
      hst[q] = h;
      storeu32(h1r + 3 * 16384 + (rowq0 + q) * 512 + hcol, (1u << 16) | f16bits(h));
    }
    for (int t = 0; t < LSEQ; ++t) {
      if (t >= 4) poll64(c3b, lane, (unsigned)(t - 2));
      const unsigned int* p = h0r + (t & 3) * 16384 + arow * 512 + 8 * lhi;
      f16x8 afr[16];
      pollload8(p, (unsigned)(t + 2), afr);
      pollload8(p + 256, (unsigned)(t + 2), afr + 8);
      if (lane == 0) astore(c2me, (unsigned)(t + 2));
      f32x4 a0 = {0,0,0,0}, a1 = {0,0,0,0}, a2 = {0,0,0,0};
#pragma unroll
      for (int kc = 0; kc < 16; ++kc) {
        a0 = __builtin_amdgcn_mfma_f32_16x16x32_f16(afr[kc], Wb1[(kc*3+0)*64+lane], a0, 0,0,0);
        a1 = __builtin_amdgcn_mfma_f32_16x16x32_f16(afr[kc], Wb1[(kc*3+1)*64+lane], a1, 0,0,0);
        a2 = __builtin_amdgcn_mfma_f32_16x16x32_f16(afr[kc], Wb1[(kc*3+2)*64+lane], a2, 0,0,0);
      }
      lds_poll(&sf[4 + mhalf], (unsigned)(t + 1));  // gh1[t] ready
      float hnew[4];
#pragma unroll
      for (int q = 0; q < 4; ++q) {
        const int row = rowq0 + q;
        float r = sig_(a0[q] + gh1buf[(0*32 + row)*16 + l16] + bR);
        float z = sig_(a1[q] + gh1buf[(1*32 + row)*16 + l16] + bZ);
        float n = tanh_(a2[q] + r * (gh1buf[(2*32 + row)*16 + l16] + bN));
        hnew[q] = (1.0f - z) * n + z * hst[q];
        hst[q] = hnew[q];
      }
      if (lane == 0) lds_post(&sf[6 + mhalf], (unsigned)(t + 1));  // consumed gh1[t]
      const unsigned int tg = (unsigned)(t + 2) << 16;
#pragma unroll
      for (int q = 0; q < 4; ++q)
        storeu32(h1r + (t & 3) * 16384 + (rowq0 + q) * 512 + hcol, tg | f16bits(hnew[q]));
#pragma unroll
      for (int q = 0; q < 4; ++q)  // y[t] (plain cached stores)
        out[(size_t)262144 + ((size_t)t * 256 + g * 32 + rowq0 + q) * 512 + hcol] = hnew[q];
      if (t == LSEQ - 1) {
#pragma unroll
        for (int q = 0; q < 4; ++q)
          out[(size_t)(g * 32 + rowq0 + q) * 1024 + 512 + hcol] = hst[q];  // carry h1
      }
    }
  } else {  // ======== role 3: consume h1[t-1], gh1 -> LDS ========
    for (int t = 0; t < LSEQ; ++t) {
      const unsigned int* p = h1r + ((t + 3) & 3) * 16384 + arow * 512 + 8 * lhi;
      f16x8 afr[16];
      pollload8(p, (unsigned)(t + 1), afr);
      pollload8(p + 256, (unsigned)(t + 1), afr + 8);
      if (lane == 0) astore(c3me, (unsigned)(t + 1));
      f32x4 a0 = {0,0,0,0}, a1 = {0,0,0,0}, a2 = {0,0,0,0};
#pragma unroll
      for (int kc = 0; kc < 16; ++kc) {
        a0 = __builtin_amdgcn_mfma_f32_16x16x32_f16(afr[kc], Wb2[(kc*3+0)*64+lane], a0, 0,0,0);
        a1 = __builtin_amdgcn_mfma_f32_16x16x32_f16(afr[kc], Wb2[(kc*3+1)*64+lane], a1, 0,0,0);
        a2 = __builtin_amdgcn_mfma_f32_16x16x32_f16(afr[kc], Wb2[(kc*3+2)*64+lane], a2, 0,0,0);
      }
      lds_poll(&sf[6 + mhalf], (unsigned)t);  // role2 consumed gh1[t-1]
#pragma unroll
      for (int q = 0; q < 4; ++q) {
        const int row = rowq0 + q;
        gh1buf[(0*32 + row)*16 + l16] = a0[q];
        gh1buf[(1*32 + row)*16 + l16] = a1[q];
        gh1buf[(2*32 + row)*16 + l16] = a2[q];
      }
      if (lane == 0) lds_post(&sf[4 + mhalf], (unsigned)(t + 1));
    }
  }
}

extern "C" void kernel_launch(void* const* d_in, const int* in_sizes, int n_in,
                              void* d_out, int out_size, void* d_ws, size_t ws_size,
                              hipStream_t stream) {
  const float* carry = (const float*)d_in[0];
  const float* x     = (const float*)d_in[1];
  const float* Wi0   = (const float*)d_in[2];
  const float* Wh0   = (const float*)d_in[3];
  const float* bh0   = (const float*)d_in[4];
  const float* Wi1   = (const float*)d_in[5];
  const float* Wh1   = (const float*)d_in[6];
  const float* bh1   = (const float*)d_in[7];
  float* out = (float*)d_out;
  char* ws = (char*)d_ws;

  prep_kernel<<<2048, 256, 0, stream>>>(Wh0, Wi1, Wh1, Wi0, ws);

  (void)hipFuncSetAttribute(reinterpret_cast<const void*>(gru_kernel),
                            hipFuncAttributeMaxDynamicSharedMemorySize, 159744);

  void* args[] = {(void*)&carry, (void*)&x, (void*)&bh0, (void*)&bh1, (void*)&out, (void*)&ws};
  (void)hipLaunchCooperativeKernel(reinterpret_cast<void*>(gru_kernel),
                                   dim3(256), dim3(512), args, 159744, stream);
}

// Round 12
// 8425.407 us; speedup vs baseline: 4.2360x; 4.2360x over previous
//
#include <hip/hip_runtime.h>

// 2-layer GRU scan: L=512, B=256, D=H=512, 3H=1536.
// Persistent cooperative kernel: 256 blocks (1/CU, LDS-pinned) x 512 threads.
// 8 groups x 32 blocks (g=bid&7); group owns 32 batch rows; layer0 step s and
// layer1 step s-1 run concurrently; ONE group barrier per super-step.
//
// R12 = R9 (8.53ms, proven) + two contention fixes:
//  (1) barrier poll throttled s_sleep(1)->s_sleep(8): R9's 256x64-lane
//      continuous atomic-load storm (~1.5TB/s of 4B IF$ traffic) inflated
//      every fabric RT; 16x less poll traffic for <=0.26us detect cost.
//  (2) role2's y-writes moved into the barrier's shadow (issued after flag
//      post, drain during the poll) instead of inside the pre-flag vmcnt(0)
//      critical drain (~1us HBM store latency off the chain per step).
// All else identical to R9: flag barrier (atomic store own slot + 32-slot
// parallel atomic poll + ballot), h-state sc0 sc1 at IF$, lockstep (loads
// always after stores land -> IF$ hits, FETCH 0.6MB/step).

#define LSEQ 512
#define TH3 1536

// ws layout (bytes)
#define WT_OFF   0                         // half WT[4][32][16][3][64][8] = 6291456
#define H0_OFF   6291456                   // half h0buf[8][2][32][512]    = 524288
#define H1_OFF   6815744                   // half h1buf[8][2][32][512]    = 524288
#define FBAR_OFF 7340032                   // flag[8][32][128B]            = 32768

typedef _Float16 f16x8 __attribute__((ext_vector_type(8)));
typedef float f32x4 __attribute__((ext_vector_type(4)));

__device__ __forceinline__ float sig_(float v) { return 1.0f / (1.0f + __expf(-v)); }
__device__ __forceinline__ float tanh_(float v) { return 2.0f / (1.0f + __expf(-2.0f * v)) - 1.0f; }

// h-state transport: IF$ coherence point (R2/R6/R9-proven).
__device__ __forceinline__ f32x4 load16b(const void* p) {
  f32x4 r;
  asm volatile("global_load_dwordx4 %0, %1, off sc0 sc1" : "=v"(r) : "v"(p));
  return r;  // NOT ready until s_waitcnt vmcnt(0)
}
__device__ __forceinline__ void store2b(_Float16* p, _Float16 v) {
  asm volatile("global_store_short %0, %1, off sc0 sc1" :: "v"(p), "v"(v) : "memory");
}
__device__ __forceinline__ void astore(unsigned int* p, unsigned int v) {
  __hip_atomic_store(p, v, __ATOMIC_RELAXED, __HIP_MEMORY_SCOPE_AGENT);
}
__device__ __forceinline__ unsigned int aload(unsigned int* p) {
  return __hip_atomic_load(p, __ATOMIC_RELAXED, __HIP_MEMORY_SCOPE_AGENT);
}

// Prologue flag barrier (R9 structure, throttled poll).
__device__ __forceinline__ void gbarrier(char* fb, unsigned int* myflag, int tid, int lane,
                                         unsigned int k) {
  __syncthreads();
  if (tid < 64) {
    const unsigned int tgt = k + 1;
    if (tid == 0) astore(myflag, tgt);
    unsigned int* p = (unsigned int*)(fb + (lane & 31) * 128);
    while (__ballot(aload(p) >= tgt) != ~0ull) __builtin_amdgcn_s_sleep(8);
  }
  __syncthreads();
}

// Weight transpose fp32 -> fp16 MFMA B-fragment layout (unchanged).
__global__ void prep_kernel(const float* __restrict__ Wh0, const float* __restrict__ Wi1,
                            const float* __restrict__ Wh1, const float* __restrict__ Wi0,
                            char* __restrict__ ws) {
  const int b = blockIdx.x;          // 2048 blocks
  const int w = b >> 9;              // 0:Wh0 1:Wi1 2:Wh1 3:Wi0
  const int k = b & 511;
  const float* src = (w == 0) ? Wh0 : (w == 1) ? Wi1 : (w == 2) ? Wh1 : Wi0;
  _Float16* dst = (_Float16*)(ws + WT_OFF);
  const int kc = k >> 5;
  const int lthi = ((k >> 3) & 3) << 4;
  const int e = k & 7;
  for (int col = threadIdx.x; col < TH3; col += 256) {
    float v = src[(size_t)k * TH3 + col];
    int nt = col >> 9, c = col & 511, cid = c >> 4, j = c & 15;
    size_t idx = (size_t)(w * 32 + cid) * 24576 + (size_t)((kc * 3 + nt) * 64 + lthi + j) * 8 + e;
    dst[idx] = (_Float16)v;
  }
  if (b == 0) {  // zero barrier flags (every call, stream-ordered)
    unsigned int* z = (unsigned int*)(ws + FBAR_OFF);
    for (int i = threadIdx.x; i < 8192; i += 256) z[i] = 0u;
  }
}

__global__ void __launch_bounds__(512, 2)
gru_kernel(const float* __restrict__ carry, const float* __restrict__ x,
           const float* __restrict__ bh0, const float* __restrict__ bh1,
           float* __restrict__ out, char* __restrict__ ws) {
  extern __shared__ char smem[];
  _Float16* Wlds = (_Float16*)smem;     // 147456 B: Wh0,Wi1,Wh1 fragment slices
  float* GH = (float*)(smem + 147456);  // 12288 B: [2 layer][3 nt][32 row][16 col]

  const int tid = threadIdx.x;
  const int wid = tid >> 6, lane = tid & 63;
  const int l16 = lane & 15, lhi = lane >> 4;
  const int mhalf = wid & 1, role = wid >> 1;  // 0:gh0 1:gi0+ep0 2:gi1+ep1 3:gh1
  const int g = blockIdx.x & 7, cid = blockIdx.x >> 3;

  _Float16* wt = (_Float16*)(ws + WT_OFF);
  _Float16* h0buf = (_Float16*)(ws + H0_OFF) + (size_t)g * 32768;  // [2 parity][32 row][512]
  _Float16* h1buf = (_Float16*)(ws + H1_OFF) + (size_t)g * 32768;
  char* fb = ws + FBAR_OFF + (size_t)g * 32 * 128;
  unsigned int* myflag = (unsigned int*)(fb + cid * 128);
  unsigned int k = 0;

  // Stage this CU's recurrent-weight fragments into LDS.
  for (int w = 0; w < 3; ++w) {
    const f16x8* s8 = (const f16x8*)(wt + (size_t)(w * 32 + cid) * 24576);
    f16x8* d8 = (f16x8*)(Wlds + w * 24576);
    for (int i = tid; i < 3072; i += 512) d8[i] = s8[i];
  }

  const int hcol = cid * 16 + l16;
  const int rowq0 = mhalf * 16 + 4 * lhi;  // acc-tile rows rowq0+q (m89-verified C/D layout)

  float bR = 0.f, bZ = 0.f, bN = 0.f;
  f32x4 hst = {0.f, 0.f, 0.f, 0.f};  // fp32 recurrent state (roles 1,2)
  if (role == 1 || role == 2) {
    const float* bh = (role == 1) ? bh0 : bh1;
    bR = bh[hcol]; bZ = bh[512 + hcol]; bN = bh[1024 + hcol];
    const int loff = (role == 1) ? 0 : 512;
    _Float16* hb = (role == 1) ? h0buf : h1buf;
#pragma unroll
    for (int q = 0; q < 4; ++q) {
      float h = carry[(size_t)(g * 32 + rowq0 + q) * 1024 + loff + hcol];
      hst[q] = h;
      store2b(&hb[16384 + (rowq0 + q) * 512 + hcol], (_Float16)h);  // prefill parity-1
    }
    asm volatile("s_waitcnt vmcnt(0)" ::: "memory");
  }
  gbarrier(fb, myflag, tid, lane, ++k);

  const f16x8* Wb0 = (const f16x8*)Wlds;                 // Wh0 frags (LDS)
  const f16x8* Wb1 = (const f16x8*)(Wlds + 24576);       // Wi1 frags (LDS)
  const f16x8* Wb2 = (const f16x8*)(Wlds + 2 * 24576);   // Wh1 frags (LDS)
  const f16x8* WbX = (const f16x8*)(wt + (size_t)(3 * 32 + cid) * 24576);  // Wi0 frags (L2)

  for (int s = 0; s <= LSEQ; ++s) {
    const int pr = (s + 1) & 1;  // parity of state[s-1]
    const int pw = s & 1;        // parity of state[s] / state[s-2]
    f32x4 a0 = {0,0,0,0}, a1 = {0,0,0,0}, a2 = {0,0,0,0};

    if (role == 0 && s < LSEQ) {            // gh0 = h0[s-1] @ Wh0
      const _Float16* Ap = h0buf + pr * 16384 + (mhalf * 16 + l16) * 512 + 8 * lhi;
      f16x8 afr[16];
#pragma unroll
      for (int kc = 0; kc < 16; ++kc) afr[kc] = __builtin_bit_cast(f16x8, load16b(Ap + kc * 32));
      asm volatile("s_waitcnt vmcnt(0)" ::: "memory");
      __builtin_amdgcn_sched_barrier(0);
#pragma unroll
      for (int kc = 0; kc < 16; ++kc) {
        a0 = __builtin_amdgcn_mfma_f32_16x16x32_f16(afr[kc], Wb0[(kc*3+0)*64+lane], a0, 0,0,0);
        a1 = __builtin_amdgcn_mfma_f32_16x16x32_f16(afr[kc], Wb0[(kc*3+1)*64+lane], a1, 0,0,0);
        a2 = __builtin_amdgcn_mfma_f32_16x16x32_f16(afr[kc], Wb0[(kc*3+2)*64+lane], a2, 0,0,0);
      }
#pragma unroll
      for (int q = 0; q < 4; ++q) {
        GH[(0*32 + rowq0 + q)*16 + l16] = a0[q];
        GH[(1*32 + rowq0 + q)*16 + l16] = a1[q];
        GH[(2*32 + rowq0 + q)*16 + l16] = a2[q];
      }
    } else if (role == 3 && s >= 1) {       // gh1 = h1[s-2] @ Wh1
      const _Float16* Ap = h1buf + pw * 16384 + (mhalf * 16 + l16) * 512 + 8 * lhi;
      f16x8 afr[16];
#pragma unroll
      for (int kc = 0; kc < 16; ++kc) afr[kc] = __builtin_bit_cast(f16x8, load16b(Ap + kc * 32));
      asm volatile("s_waitcnt vmcnt(0)" ::: "memory");
      __builtin_amdgcn_sched_barrier(0);
#pragma unroll
      for (int kc = 0; kc < 16; ++kc) {
        a0 = __builtin_amdgcn_mfma_f32_16x16x32_f16(afr[kc], Wb2[(kc*3+0)*64+lane], a0, 0,0,0);
        a1 = __builtin_amdgcn_mfma_f32_16x16x32_f16(afr[kc], Wb2[(kc*3+1)*64+lane], a1, 0,0,0);
        a2 = __builtin_amdgcn_mfma_f32_16x16x32_f16(afr[kc], Wb2[(kc*3+2)*64+lane], a2, 0,0,0);
      }
#pragma unroll
      for (int q = 0; q < 4; ++q) {
        GH[((3+0)*32 + rowq0 + q)*16 + l16] = a0[q];
        GH[((3+1)*32 + rowq0 + q)*16 + l16] = a1[q];
        GH[((3+2)*32 + rowq0 + q)*16 + l16] = a2[q];
      }
    } else if (role == 1 && s < LSEQ) {     // gi0 = x[s] @ Wi0
      const float* xp = x + ((size_t)s * 256 + g * 32 + mhalf * 16 + l16) * 512 + 8 * lhi;
#pragma unroll
      for (int kc = 0; kc < 16; ++kc) {
        f32x4 xa = *(const f32x4*)(xp + kc * 32);
        f32x4 xb = *(const f32x4*)(xp + kc * 32 + 4);
        f16x8 a;
        a[0]=(_Float16)xa[0]; a[1]=(_Float16)xa[1]; a[2]=(_Float16)xa[2]; a[3]=(_Float16)xa[3];
        a[4]=(_Float16)xb[0]; a[5]=(_Float16)xb[1]; a[6]=(_Float16)xb[2]; a[7]=(_Float16)xb[3];
        a0 = __builtin_amdgcn_mfma_f32_16x16x32_f16(a, WbX[(kc*3+0)*64+lane], a0, 0,0,0);
        a1 = __builtin_amdgcn_mfma_f32_16x16x32_f16(a, WbX[(kc*3+1)*64+lane], a1, 0,0,0);
        a2 = __builtin_amdgcn_mfma_f32_16x16x32_f16(a, WbX[(kc*3+2)*64+lane], a2, 0,0,0);
      }
    } else if (role == 2 && s >= 1) {       // gi1 = h0[s-1] @ Wi1
      const _Float16* Ap = h0buf + pr * 16384 + (mhalf * 16 + l16) * 512 + 8 * lhi;
      f16x8 afr[16];
#pragma unroll
      for (int kc = 0; kc < 16; ++kc) afr[kc] = __builtin_bit_cast(f16x8, load16b(Ap + kc * 32));
      asm volatile("s_waitcnt vmcnt(0)" ::: "memory");
      __builtin_amdgcn_sched_barrier(0);
#pragma unroll
      for (int kc = 0; kc < 16; ++kc) {
        a0 = __builtin_amdgcn_mfma_f32_16x16x32_f16(afr[kc], Wb1[(kc*3+0)*64+lane], a0, 0,0,0);
        a1 = __builtin_amdgcn_mfma_f32_16x16x32_f16(afr[kc], Wb1[(kc*3+1)*64+lane], a1, 0,0,0);
        a2 = __builtin_amdgcn_mfma_f32_16x16x32_f16(afr[kc], Wb1[(kc*3+2)*64+lane], a2, 0,0,0);
      }
    }
    __syncthreads();  // gh accs visible in LDS

    if (role == 1 && s < LSEQ) {            // layer-0 epilogue -> h0[s]
#pragma unroll
      for (int q = 0; q < 4; ++q) {
        const int row = rowq0 + q;
        float r = sig_(a0[q] + GH[(0*32 + row)*16 + l16] + bR);
        float z = sig_(a1[q] + GH[(1*32 + row)*16 + l16] + bZ);
        float n = tanh_(a2[q] + r * (GH[(2*32 + row)*16 + l16] + bN));
        float h = (1.0f - z) * n + z * hst[q];
        hst[q] = h;
        store2b(&h0buf[pw * 16384 + row * 512 + hcol], (_Float16)h);
        if (s == LSEQ - 1) out[(size_t)(g * 32 + row) * 1024 + hcol] = h;  // carry h0
      }
      asm volatile("s_waitcnt vmcnt(0)" ::: "memory");
    } else if (role == 2 && s >= 1) {       // layer-1 epilogue -> h1[s-1]
#pragma unroll
      for (int q = 0; q < 4; ++q) {
        const int row = rowq0 + q;
        float r = sig_(a0[q] + GH[((3+0)*32 + row)*16 + l16] + bR);
        float z = sig_(a1[q] + GH[((3+1)*32 + row)*16 + l16] + bZ);
        float n = tanh_(a2[q] + r * (GH[((3+2)*32 + row)*16 + l16] + bN));
        float h = (1.0f - z) * n + z * hst[q];
        hst[q] = h;
        store2b(&h1buf[pr * 16384 + row * 512 + hcol], (_Float16)h);
        if (s == LSEQ) out[(size_t)(g * 32 + row) * 1024 + 512 + hcol] = h;  // carry h1
      }
      asm volatile("s_waitcnt vmcnt(0)" ::: "memory");
      // y[s-1] writes moved into the barrier's shadow below (R12 change #2).
    }

    // ---- inlined step barrier (R12): post flag, issue y in its shadow, poll ----
    ++k;
    __syncthreads();  // all waves' VMEM drained (vmcnt(0) before s_barrier)
    {
      const unsigned int tgt = k + 1;
      if (tid == 0) astore(myflag, tgt);
      if (role == 2 && s >= 1) {  // y[s-1] = hst (plain cached stores; drain hidden under poll)
#pragma unroll
        for (int q = 0; q < 4; ++q)
          out[(size_t)262144 + ((size_t)(s - 1) * 256 + g * 32 + rowq0 + q) * 512 + hcol] = hst[q];
      }
      if (tid < 64) {
        unsigned int* p = (unsigned int*)(fb + (lane & 31) * 128);
        while (__ballot(aload(p) >= tgt) != ~0ull) __builtin_amdgcn_s_sleep(8);
      }
    }
    __syncthreads();
  }
}

extern "C" void kernel_launch(void* const* d_in, const int* in_sizes, int n_in,
                              void* d_out, int out_size, void* d_ws, size_t ws_size,
                              hipStream_t stream) {
  const float* carry = (const float*)d_in[0];
  const float* x     = (const float*)d_in[1];
  const float* Wi0   = (const float*)d_in[2];
  const float* Wh0   = (const float*)d_in[3];
  const float* bh0   = (const float*)d_in[4];
  const float* Wi1   = (const float*)d_in[5];
  const float* Wh1   = (const float*)d_in[6];
  const float* bh1   = (const float*)d_in[7];
  float* out = (float*)d_out;
  char* ws = (char*)d_ws;

  prep_kernel<<<2048, 256, 0, stream>>>(Wh0, Wi1, Wh1, Wi0, ws);

  (void)hipFuncSetAttribute(reinterpret_cast<const void*>(gru_kernel),
                            hipFuncAttributeMaxDynamicSharedMemorySize, 159744);

  void* args[] = {(void*)&carry, (void*)&x, (void*)&bh0, (void*)&bh1, (void*)&out, (void*)&ws};
  (void)hipLaunchCooperativeKernel(reinterpret_cast<void*>(gru_kernel),
                                   dim3(256), dim3(512), args, 159744, stream);
}